// Round 12
// baseline (3415.505 us; speedup 1.0000x reference)
//
#include <hip/hip_runtime.h>
#include <math.h>
#include <stdint.h>

#define BB 128   // batch
#define SS 128   // seq len
#define EE 300   // embed dim
#define HH 256   // per-direction hidden
#define G4 1024  // 4*HH gate width
#define TT 16    // tagset
#define NEGV -10000.0f
#define START_TAG 14
#define STOP_TAG 15
#define NRB 512  // recur-role blocks
#define NXB 4096 // xproj-role blocks (8-row tiles: 2048 per dir)

typedef float f32x4 __attribute__((ext_vector_type(4)));

__device__ __forceinline__ float sigm(float x) { return 1.0f / (1.0f + expf(-x)); }

__device__ __forceinline__ float4 shfl_xor4(float4 v, int m) {
  float4 r;
  r.x = __shfl_xor(v.x, m); r.y = __shfl_xor(v.y, m);
  r.z = __shfl_xor(v.z, m); r.w = __shfl_xor(v.w, m);
  return r;
}
__device__ __forceinline__ void add4(float4& a, const float4& b) {
  a.x += b.x; a.y += b.y; a.z += b.z; a.w += b.w;
}

// LLC-coherent loads (sc0+sc1 bypass L1/L2 -> device coherent point).
// Load/store class proven R5-R11 on this chip (absmax 0 across 6 rounds).
__device__ __forceinline__ void load_pairs8(const float* p, f32x4& a, f32x4& b) {
  asm volatile("global_load_dwordx4 %0, %2, off sc0 sc1\n\t"
               "global_load_dwordx4 %1, %2, off offset:16 sc0 sc1\n\t"
               "s_waitcnt vmcnt(0)"
               : "=&v"(a), "=&v"(b) : "v"(p) : "memory");
}
__device__ __forceinline__ f32x4 load_f4_llc(const float* p) {
  f32x4 v;
  asm volatile("global_load_dwordx4 %0, %1, off sc0 sc1\n\t"
               "s_waitcnt vmcnt(0)"
               : "=v"(v) : "v"(p) : "memory");
  return v;
}
__device__ __forceinline__ int load_int_llc(const int* p) {
  int v;
  asm volatile("global_load_dword %0, %1, off sc0 sc1\n\t"
               "s_waitcnt vmcnt(0)"
               : "=v"(v) : "v"(p) : "memory");
  return v;
}
// 8B relaxed agent-scope atomic stores (go to the coherent point; proven).
__device__ __forceinline__ void store_pair_llc(float2* p, float h, int stamp) {
  uint64_t bits = ((uint64_t)(uint32_t)stamp << 32) | (uint64_t)__float_as_uint(h);
  __hip_atomic_store((uint64_t*)p, bits, __ATOMIC_RELAXED, __HIP_MEMORY_SCOPE_AGENT);
}
__device__ __forceinline__ void store_f2_llc(float* p, float a, float b) {
  uint64_t bits = ((uint64_t)__float_as_uint(b) << 32) | (uint64_t)__float_as_uint(a);
  __hip_atomic_store((uint64_t*)p, bits, __ATOMIC_RELAXED, __HIP_MEMORY_SCOPE_AGENT);
}

// ---------------- prep: weight transposes + bias folding + stamp zero ----------------
__global__ void k_prep(const float* __restrict__ Wih_f, const float* __restrict__ Whh_f,
                       const float* __restrict__ bih_f, const float* __restrict__ bhh_f,
                       const float* __restrict__ Wih_b, const float* __restrict__ Whh_b,
                       const float* __restrict__ bih_b, const float* __restrict__ bhh_b,
                       float* __restrict__ WihT, float* __restrict__ Whh4,
                       float* __restrict__ bsum, float* __restrict__ hpairz,
                       int* __restrict__ xstamp) {
  int id = blockIdx.x * blockDim.x + threadIdx.x;
  const int N1 = 2 * EE * G4;
  const int N2 = 2 * HH * G4;
  const int N3 = 2 * G4;
  const int N4 = 3 * 2 * BB * HH * 2;   // hpair floats
  const int N5 = 2 * SS * BB * 8;       // xstamp words
  if (id < N1) {
    int d = id / (EE * G4); int r = id % (EE * G4);
    int e = r / G4; int j = r % G4;
    const float* W = d ? Wih_b : Wih_f;
    WihT[id] = W[j * EE + e];
  } else if (id < N1 + N2) {
    int t = id - N1;
    int d = t / (HH * G4); int r = t % (HH * G4);
    int k = r / G4; int q = r % G4; int u = q >> 2; int g = q & 3;
    const float* W = d ? Whh_b : Whh_f;
    Whh4[t] = W[(g * HH + u) * HH + k];
  } else if (id < N1 + N2 + N3) {
    int t = id - N1 - N2;
    int d = t / G4; int j = t % G4;
    bsum[t] = d ? (bih_b[j] + bhh_b[j]) : (bih_f[j] + bhh_f[j]);
  } else if (id < N1 + N2 + N3 + N4) {
    hpairz[id - N1 - N2 - N3] = 0.0f;
  } else if (id < N1 + N2 + N3 + N4 + N5) {
    xstamp[id - N1 - N2 - N3 - N4] = 0;
  }
}

// ---------------- mixed kernel: recur (blocks 0..511) + xproj (512..4607) ----------------
// Deadlock-proof: launch_bounds(256,4) caps VGPR at 128 -> 1024 block-slots on
// the device; 512 recur blocks can never exclude xproj blocks regardless of
// dispatch order; xproj blocks never wait; all recur spins are sleep-throttled.
__global__ __launch_bounds__(256, 4) void k_main(
    const float4* __restrict__ Wg, const float* __restrict__ h0,
    const float* __restrict__ c0, float2* __restrict__ hpair,
    float* __restrict__ hall, float* __restrict__ xp4, int* __restrict__ xstamp,
    const int* __restrict__ sent, const float* __restrict__ emb,
    const float* __restrict__ WihT, const float* __restrict__ bsum) {
  __shared__ __align__(16) float smem[2432];   // recur: hsh[2][1152]; xproj: xs[8][300]
  __shared__ int idxs[8];
  int blk = blockIdx.x, tid = threadIdx.x;

  if (blk < NRB) {
    // ================= recur role (R11 kernel; xg now stamped-LLC) =================
    int d = blk >> 8, bg = (blk >> 3) & 31, sl = blk & 7;
    int bbase = bg * 4;
    int u = tid >> 3, kc = tid & 7;
    int uglob = sl * 32 + u;

    float4 wreg[32];
    {
      const float4* Wd = Wg + (size_t)d * (HH * HH) + (size_t)(kc * 32) * HH + uglob;
#pragma unroll
      for (int kk = 0; kk < 32; ++kk) wreg[kk] = Wd[(size_t)kk * HH];
    }
    int b_own = ((kc & 1) << 1) | ((kc >> 1) & 1);
    float c_reg = c0[((size_t)d * BB + bbase + b_own) * HH + uglob];
    bool up0 = (kc & 1), up1 = (kc & 2);

    int sb = tid >> 6;
    int k4 = (tid & 63) * 4;
    int ldoff = sb * 288 + (k4 >> 5) * 36 + (k4 & 31);

    for (int step = 0; step < SS; ++step) {
      int s = d ? (SS - 1 - step) : step;
      int pb = step & 1;

      // ---- xg: poll tile stamp (produced by xproj role), then dependent load ----
      float4 xg;
      {
        const int* sp = xstamp + ((size_t)(d * SS + s) * BB + bbase + b_own) * 8 + sl;
        while (load_int_llc(sp) != 1) __builtin_amdgcn_s_sleep(8);
        f32x4 xv = load_f4_llc(xp4 + ((size_t)(d * SS + s) * BB + bbase + b_own) * G4 +
                               uglob * 4);
        xg = make_float4(xv[0], xv[1], xv[2], xv[3]);
      }

      // ---- stage h(step-1): poll own stamped pairs (detect == data) ----
      float* ldst = &smem[pb * 1152 + ldoff];
      if (step == 0) {
        const float* ps = h0 + ((size_t)d * BB + bbase + sb) * HH + k4;
        *(f32x4*)ldst = *(const f32x4*)ps;
      } else {
        int slot_r = (step + 2) % 3;
        const float* ps = (const float*)(hpair +
            ((size_t)(slot_r * 2 + d) * BB + bbase + sb) * HH + k4);
        f32x4 v0, v1;
        load_pairs8(ps, v0, v1);
        while (__float_as_int(v0[1]) != step || __float_as_int(v0[3]) != step ||
               __float_as_int(v1[1]) != step || __float_as_int(v1[3]) != step) {
          __builtin_amdgcn_s_sleep(1);
          load_pairs8(ps, v0, v1);
        }
        f32x4 q = {v0[0], v0[2], v1[0], v1[2]};
        *(f32x4*)ldst = q;
      }
      __syncthreads();   // the ONLY barrier per step

      // ---- gate partials over this thread's 32-k chunk (4 batches) ----
      const float* hb = &smem[pb * 1152];
      float4 a[4];
#pragma unroll
      for (int b = 0; b < 4; ++b) a[b] = make_float4(0.f, 0.f, 0.f, 0.f);
#pragma unroll
      for (int kk4 = 0; kk4 < 8; ++kk4) {
        float hvv[4][4];
#pragma unroll
        for (int b = 0; b < 4; ++b)
          *(f32x4*)&hvv[b][0] = *(const f32x4*)&hb[b * 288 + kc * 36 + kk4 * 4];
#pragma unroll
        for (int j = 0; j < 4; ++j) {
          float4 w = wreg[kk4 * 4 + j];
#pragma unroll
          for (int b = 0; b < 4; ++b) {
            float hj = hvv[b][j];
            a[b].x += w.x * hj; a[b].y += w.y * hj;
            a[b].z += w.z * hj; a[b].w += w.w * hj;
          }
        }
      }

      // ---- reduce-scatter over kc (3 rounds; kc^4 lanes duplicate, benign) ----
#pragma unroll
      for (int j = 0; j < 2; ++j) {
        float4 snd = up0 ? a[j] : a[j + 2];
        float4 rcv = shfl_xor4(snd, 1);
        if (!up0) add4(a[j], rcv); else add4(a[j + 2], rcv);
      }
      float4 v0 = up0 ? a[2] : a[0];
      float4 v1 = up0 ? a[3] : a[1];
      {
        float4 snd = up1 ? v0 : v1;
        float4 rcv = shfl_xor4(snd, 2);
        if (!up1) add4(v0, rcv); else add4(v1, rcv);
      }
      float4 keep = up1 ? v1 : v0;
      {
        float4 rcv = shfl_xor4(keep, 4);
        add4(keep, rcv);
      }

      // ---- nonlinearity + publish (fire-and-forget) ----
      float ii = keep.x + xg.x, ff = keep.y + xg.y;
      float gg = keep.z + xg.z, oo = keep.w + xg.w;
      c_reg = sigm(ff) * c_reg + sigm(ii) * tanhf(gg);
      float hn = sigm(oo) * tanhf(c_reg);

      if (kc < 4) {
        store_pair_llc(&hpair[((size_t)((step % 3) * 2 + d) * BB + bbase + b_own) * HH + uglob],
                       hn, step + 1);
        hall[(((size_t)d * SS + step) * BB + bbase + b_own) * HH + uglob] = hn;
      }
      // no trailing barrier: dbuf parity + next step's stage barrier order smem reuse
    }
  } else {
    // ================= xproj role: one 8-row tile, production-ordered =================
    int xb = blk - NRB;
    int d = xb & 1;
    int t = d ? (2047 - (xb >> 1)) : (xb >> 1);   // d0: s ascending; d1: s descending

    if (tid < 8) {
      int sb = t * 8 + tid;
      int s = sb >> 7, b = sb & 127;
      idxs[tid] = sent[b * SS + s];
    }
    __syncthreads();
    for (int i = tid; i < 8 * 75; i += 256) {
      int r = i / 75, e4 = i % 75;
      *(f32x4*)&smem[r * 300 + e4 * 4] = ((const f32x4*)(emb + (size_t)idxs[r] * EE))[e4];
    }
    __syncthreads();

    const float* WT = WihT + (size_t)d * EE * G4;
    float acc0[8], acc1[8], acc2[8], acc3[8];
#pragma unroll
    for (int i = 0; i < 8; ++i) { acc0[i] = 0.f; acc1[i] = 0.f; acc2[i] = 0.f; acc3[i] = 0.f; }

    for (int e4 = 0; e4 < 75; ++e4) {
      f32x4 xv[8];
#pragma unroll
      for (int i = 0; i < 8; ++i) xv[i] = *(const f32x4*)&smem[i * 300 + e4 * 4];
      const float* rowb = WT + (size_t)e4 * 4 * G4;
#pragma unroll
      for (int j = 0; j < 4; ++j) {
        const float* row = rowb + (size_t)j * G4;
        float w0 = row[tid];
        float w1 = row[tid + 256];
        float w2 = row[tid + 512];
        float w3 = row[tid + 768];
#pragma unroll
        for (int i = 0; i < 8; ++i) {
          float x = xv[i][j];
          acc0[i] += w0 * x; acc1[i] += w1 * x; acc2[i] += w2 * x; acc3[i] += w3 * x;
        }
      }
    }
    float b0 = bsum[d * G4 + tid];
    float b1 = bsum[d * G4 + tid + 256];
    float b2 = bsum[d * G4 + tid + 512];
    float b3 = bsum[d * G4 + tid + 768];
#pragma unroll
    for (int i = 0; i < 8; ++i) {
      int sb = t * 8 + i;
      int s = sb >> 7, b = sb & 127;
      float* base = xp4 + ((size_t)(d * SS + s) * BB + b) * G4 + tid * 4;
      store_f2_llc(base, acc0[i] + b0, acc1[i] + b1);
      store_f2_llc(base + 2, acc2[i] + b2, acc3[i] + b3);
    }
    __syncthreads();   // per-wave vmcnt drain before barrier -> all stores at LLC
    if (tid < 64) {
      int r = tid >> 3, sl = tid & 7;
      int sb = t * 8 + r;
      int s = sb >> 7, b = sb & 127;
      __hip_atomic_store(xstamp + ((size_t)(d * SS + s) * BB + b) * 8 + sl, 1,
                         __ATOMIC_RELAXED, __HIP_MEMORY_SCOPE_AGENT);
    }
  }
}

// ---------------- feats: featsF[b][s][t] = concat(h_f,h_b) dot W_out row ----------------
__global__ void k_feats(const float* __restrict__ hall, const float* __restrict__ Wout,
                        float* __restrict__ featsF) {
  __shared__ __align__(16) float h2[16][516];
  int b = blockIdx.x >> 3;
  int sg = blockIdx.x & 7;
  int tid = threadIdx.x;

  for (int i = tid; i < 16 * 128; i += 256) {
    int r = i >> 7, seg = i & 127;
    int s = sg * 16 + r;
    f32x4 v;
    if (seg < 64)
      v = *(const f32x4*)&hall[(((size_t)0 * SS + s) * BB + b) * HH + seg * 4];
    else
      v = *(const f32x4*)&hall[(((size_t)1 * SS + (SS - 1 - s)) * BB + b) * HH + (seg - 64) * 4];
    *(f32x4*)&h2[r][seg * 4] = v;
  }
  __syncthreads();

  int sloc = tid >> 4, t = tid & 15;
  const float* wrow = Wout + t * 512;
  float p = 0.f;
  for (int j = 0; j < 128; ++j) {
    f32x4 hv = *(const f32x4*)&h2[sloc][j * 4];
    f32x4 wv = *(const f32x4*)&wrow[j * 4];
    p += hv[0] * wv[0] + hv[1] * wv[1] + hv[2] * wv[2] + hv[3] * wv[3];
  }
  featsF[((size_t)b * SS + sg * 16 + sloc) * TT + t] = p;
}

// ---------------- Viterbi (backpointers in LDS) ----------------
__global__ void k_viterbi(const float* __restrict__ featsF, const float* __restrict__ b_out,
                          const float* __restrict__ trans, float* __restrict__ out) {
  __shared__ float tr[TT * TT];
  __shared__ unsigned char bpl[16][SS][TT];
  int tid = threadIdx.x;
  if (tid < TT * TT) tr[tid] = trans[tid];
  __syncthreads();

  int bg = tid >> 4;
  int next = tid & 15;
  int b = blockIdx.x * 16 + bg;
  float fv = (next == START_TAG) ? 0.0f : NEGV;
  float bo = b_out[next];
  const float* fF = featsF + (size_t)b * SS * TT;

  for (int s = 0; s < SS; ++s) {
    float best = -INFINITY; int arg = 0;
#pragma unroll
    for (int prev = 0; prev < TT; ++prev) {
      float fvp = __shfl(fv, prev, 16);
      float cand = fvp + tr[next * TT + prev];
      if (cand > best) { best = cand; arg = prev; }
    }
    float feat = fF[s * TT + next] + bo;
    fv = best + feat;
    bpl[bg][s][next] = (unsigned char)arg;
  }

  float bv = fv + tr[STOP_TAG * TT + next];
  int bi = next;
#pragma unroll
  for (int off = 8; off; off >>= 1) {
    float ov = __shfl_down(bv, off, 16);
    int oi = __shfl_down(bi, off, 16);
    if (ov > bv || (ov == bv && oi < bi)) { bv = ov; bi = oi; }
  }
  if (next == 0) {
    out[b] = bv;
    int tag = bi;
    float* po = out + BB + (size_t)b * SS;
    for (int s = SS - 1; s >= 0; --s) {
      po[s] = (float)tag;
      tag = bpl[bg][s][tag];
    }
  }
}

// ---------------- host ----------------
extern "C" void kernel_launch(void* const* d_in, const int* in_sizes, int n_in,
                              void* d_out, int out_size, void* d_ws, size_t ws_size,
                              hipStream_t stream) {
  const int*   sent  = (const int*)d_in[0];
  const float* emb   = (const float*)d_in[1];
  const float* Wih_f = (const float*)d_in[2];
  const float* Whh_f = (const float*)d_in[3];
  const float* bih_f = (const float*)d_in[4];
  const float* bhh_f = (const float*)d_in[5];
  const float* Wih_b = (const float*)d_in[6];
  const float* Whh_b = (const float*)d_in[7];
  const float* bih_b = (const float*)d_in[8];
  const float* bhh_b = (const float*)d_in[9];
  const float* Wout  = (const float*)d_in[10];
  const float* b_out = (const float*)d_in[11];
  const float* trans = (const float*)d_in[12];
  const float* h0    = (const float*)d_in[13];
  const float* c0    = (const float*)d_in[14];

  float* ws = (float*)d_ws;
  size_t off = 0;
  float* xp4    = ws + off; off += (size_t)2 * SS * BB * G4;          // 33,554,432 fl
  int*   xstamp = (int*)(ws + off); off += (size_t)2 * SS * BB * 8;   //    262,144 w
  float* WihT   = ws + off; off += (size_t)2 * EE * G4;               //    614,400
  float* Whh4   = ws + off; off += (size_t)2 * HH * G4;               //    524,288
  float* bsum   = ws + off; off += (size_t)2 * G4;                    //      2,048
  float* featsF = ws + off; off += (size_t)BB * SS * TT;              //    262,144
  float* hall   = ws + off; off += (size_t)2 * SS * BB * HH;          //  8,388,608
  float* hpairf = ws + off; off += (size_t)3 * 2 * BB * HH * 2;       //    393,216

  const int NPREP = 2 * EE * G4 + 2 * HH * G4 + 2 * G4 +
                    3 * 2 * BB * HH * 2 + 2 * SS * BB * 8;
  k_prep<<<(NPREP + 255) / 256, 256, 0, stream>>>(Wih_f, Whh_f, bih_f, bhh_f,
                                                  Wih_b, Whh_b, bih_b, bhh_b,
                                                  WihT, Whh4, bsum, hpairf, xstamp);

  k_main<<<NRB + NXB, 256, 0, stream>>>((const float4*)Whh4, h0, c0,
                                        (float2*)hpairf, hall, xp4, xstamp,
                                        sent, emb, WihT, bsum);

  k_feats<<<1024, 256, 0, stream>>>(hall, Wout, featsF);
  k_viterbi<<<8, 256, 0, stream>>>(featsF, b_out, trans, (float*)d_out);
}

// Round 13
// 1172.661 us; speedup vs baseline: 2.9126x; 2.9126x over previous
//
#include <hip/hip_runtime.h>
#include <math.h>
#include <stdint.h>

#define BB 128   // batch
#define SS 128   // seq len
#define EE 300   // embed dim
#define HH 256   // per-direction hidden
#define G4 1024  // 4*HH gate width
#define TT 16    // tagset
#define NEGV -10000.0f
#define START_TAG 14
#define STOP_TAG 15
#define NRB 256  // recur-role blocks (R5 partition: 2 dirs x 16 groups x 8 slices)
#define NXT 2048 // xproj-role blocks (16-row tiles: 1024 per dir)

typedef float f32x4 __attribute__((ext_vector_type(4)));
typedef int   i32x4 __attribute__((ext_vector_type(4)));

__device__ __forceinline__ float sigm(float x) { return 1.0f / (1.0f + expf(-x)); }

__device__ __forceinline__ float4 shfl_xor4(float4 v, int m) {
  float4 r;
  r.x = __shfl_xor(v.x, m); r.y = __shfl_xor(v.y, m);
  r.z = __shfl_xor(v.z, m); r.w = __shfl_xor(v.w, m);
  return r;
}
__device__ __forceinline__ void add4(float4& a, const float4& b) {
  a.x += b.x; a.y += b.y; a.z += b.z; a.w += b.w;
}

// LLC-coherent loads (sc0+sc1 bypass L1/L2 -> device coherent point).
// Load/store class proven R5-R11 (absmax 0 across 6 passing rounds).
__device__ __forceinline__ void load_f8_llc(const float* p, f32x4& a, f32x4& b) {
  asm volatile("global_load_dwordx4 %0, %2, off sc0 sc1\n\t"
               "global_load_dwordx4 %1, %2, off offset:16 sc0 sc1\n\t"
               "s_waitcnt vmcnt(0)"
               : "=&v"(a), "=&v"(b) : "v"(p) : "memory");
}
__device__ __forceinline__ void load_tags8(const int* p, i32x4& a, i32x4& b) {
  asm volatile("global_load_dwordx4 %0, %2, off sc0 sc1\n\t"
               "global_load_dwordx4 %1, %2, off offset:16 sc0 sc1\n\t"
               "s_waitcnt vmcnt(0)"
               : "=&v"(a), "=&v"(b) : "v"(p) : "memory");
}
__device__ __forceinline__ f32x4 load_f4_llc(const float* p) {
  f32x4 v;
  asm volatile("global_load_dwordx4 %0, %1, off sc0 sc1\n\t"
               "s_waitcnt vmcnt(0)"
               : "=v"(v) : "v"(p) : "memory");
  return v;
}
__device__ __forceinline__ int load_int_llc(const int* p) {
  int v;
  asm volatile("global_load_dword %0, %1, off sc0 sc1\n\t"
               "s_waitcnt vmcnt(0)"
               : "=v"(v) : "v"(p) : "memory");
  return v;
}
// 8B relaxed agent-scope atomic store (goes to the coherent point; proven).
__device__ __forceinline__ void store_f2_llc(float* p, float a, float b) {
  uint64_t bits = ((uint64_t)__float_as_uint(b) << 32) | (uint64_t)__float_as_uint(a);
  __hip_atomic_store((uint64_t*)p, bits, __ATOMIC_RELAXED, __HIP_MEMORY_SCOPE_AGENT);
}

// ---------------- prep: weight transposes + bias folding + tag/stamp zero ----------------
__global__ void k_prep(const float* __restrict__ Wih_f, const float* __restrict__ Whh_f,
                       const float* __restrict__ bih_f, const float* __restrict__ bhh_f,
                       const float* __restrict__ Wih_b, const float* __restrict__ Whh_b,
                       const float* __restrict__ bih_b, const float* __restrict__ bhh_b,
                       float* __restrict__ WihT, float* __restrict__ Whh4,
                       float* __restrict__ bsum, int* __restrict__ ctr,
                       int* __restrict__ xstamp) {
  int id = blockIdx.x * blockDim.x + threadIdx.x;
  const int N1 = 2 * EE * G4;
  const int N2 = 2 * HH * G4;
  const int N3 = 2 * G4;
  const int N4 = 32 * 256;          // tag regions
  const int N5 = 2 * SS * BB * 8;   // xstamp words
  if (id < N1) {
    int d = id / (EE * G4); int r = id % (EE * G4);
    int e = r / G4; int j = r % G4;
    const float* W = d ? Wih_b : Wih_f;
    WihT[id] = W[j * EE + e];
  } else if (id < N1 + N2) {
    int t = id - N1;
    int d = t / (HH * G4); int r = t % (HH * G4);
    int k = r / G4; int q = r % G4; int u = q >> 2; int g = q & 3;
    const float* W = d ? Whh_b : Whh_f;
    Whh4[t] = W[(g * HH + u) * HH + k];
  } else if (id < N1 + N2 + N3) {
    int t = id - N1 - N2;
    int d = t / G4; int j = t % G4;
    bsum[t] = d ? (bih_b[j] + bhh_b[j]) : (bih_f[j] + bhh_f[j]);
  } else if (id < N1 + N2 + N3 + N4) {
    ctr[id - N1 - N2 - N3] = 0;
  } else if (id < N1 + N2 + N3 + N4 + N5) {
    xstamp[id - N1 - N2 - N3 - N4] = 0;
  }
}

// ---------------- mixed kernel: recur (blocks 0..255, R5-proven) + xproj (256..2303) ----------------
// Capacity/liveness: launch_bounds(256,2) -> VGPR cap 256 (R5's ~176 recur path
// fits, NO weight spill) -> 512 block-slots; 256 recur blocks always fit; xproj
// blocks never wait on anything; recur spins are bounded-traffic (R5 protocol)
// or sleep-throttled (xg stamps). Deadlock impossible: one class never waits.
__global__ __launch_bounds__(256, 2) void k_main(
    const float4* __restrict__ Wg, const float* __restrict__ Wout,
    const float* __restrict__ h0, const float* __restrict__ c0,
    float* __restrict__ hbuf, float* __restrict__ featsP, int* __restrict__ ctr,
    float* __restrict__ xp4, int* __restrict__ xstamp,
    const int* __restrict__ sent, const float* __restrict__ emb,
    const float* __restrict__ WihT, const float* __restrict__ bsum) {
  __shared__ __align__(16) float smem[4800];  // recur: hshS[2304]; xproj: xs[16][300]
  __shared__ float hloc[8 * 33];
  __shared__ float WoL[16 * 33];
  __shared__ int idxs[16];
  int blk = blockIdx.x, tid = threadIdx.x;

  if (blk < NRB) {
    // ================= recur role: R5 protocol verbatim + stamped xg =================
    int d = blk >> 7, bg = (blk >> 3) & 15, sl = blk & 7;
    int bbase = bg * 8;
    int u = tid >> 3, kc = tid & 7;
    int uglob = sl * 32 + u;
    int* tagsg = ctr + (d * 16 + bg) * 256 + 64;   // tags[sl] = last finished step + 1

    for (int i = tid; i < 16 * 32; i += 256) {
      int t = i >> 5, uu = i & 31;
      WoL[t * 33 + uu] = Wout[t * 512 + d * HH + sl * 32 + uu];
    }

    // Whh slice -> registers (the invariant R12 broke; (256,2) keeps it)
    float4 wreg[32];
    {
      const float4* Wd = Wg + (size_t)d * (HH * HH) + (size_t)(kc * 32) * HH + uglob;
#pragma unroll
      for (int kk = 0; kk < 32; ++kk) wreg[kk] = Wd[(size_t)kk * HH];
    }
    int b_own = ((kc & 1) << 2) | (kc & 2) | ((kc >> 2) & 1);
    float c_reg = c0[((size_t)d * BB + bbase + b_own) * HH + uglob];
    bool up0 = (kc & 1), up1 = (kc & 2), up2 = (kc & 4);

    // contiguous-8 staging into kc-swizzled LDS (R5 layout)
    float* ldst = &smem[(tid >> 5) * 288 + ((tid & 31) >> 2) * 36 + (tid & 3) * 8];

    for (int step = 0; step < SS; ++step) {
      int s = d ? (SS - 1 - step) : step;

      // ---- xg: poll tile stamp (xproj role), then dependent LLC load ----
      float4 xg;
      {
        const int* sp = xstamp + ((size_t)(d * SS + s) * BB + bbase + b_own) * 8 + sl;
        while (load_int_llc(sp) != 1) __builtin_amdgcn_s_sleep(4);
        f32x4 xv = load_f4_llc(xp4 + ((size_t)(d * SS + s) * BB + bbase + b_own) * G4 +
                               uglob * 4);
        xg = make_float4(xv[0], xv[1], xv[2], xv[3]);
      }

      // ---- R5: all-thread tag poll, then h load -> LDS ----
      if (step == 0) {
        const float* ps = h0 + ((size_t)d * BB + bbase) * HH + (tid << 3);
        *(f32x4*)ldst = *(const f32x4*)ps;
        *(f32x4*)(ldst + 4) = *(const f32x4*)(ps + 4);
      } else {
        i32x4 ta, tb;
        int m;
        do {
          load_tags8(tagsg, ta, tb);
          int m0 = min(min(ta[0], ta[1]), min(ta[2], ta[3]));
          int m1 = min(min(tb[0], tb[1]), min(tb[2], tb[3]));
          m = min(m0, m1);
        } while (m < step);
        const float* ps = hbuf + ((size_t)((step - 1) % 3) * 2 + d) * BB * HH +
                          (size_t)bbase * HH + (tid << 3);
        f32x4 a, b;
        load_f8_llc(ps, a, b);
        *(f32x4*)ldst = a;
        *(f32x4*)(ldst + 4) = b;
      }
      __syncthreads();

      // ---- gate partials over this thread's 32-k chunk (8 batches) ----
      float4 a[8];
#pragma unroll
      for (int b = 0; b < 8; ++b) a[b] = make_float4(0.f, 0.f, 0.f, 0.f);
#pragma unroll
      for (int kk4 = 0; kk4 < 8; ++kk4) {
        float hvv[8][4];
#pragma unroll
        for (int b = 0; b < 8; ++b)
          *(f32x4*)&hvv[b][0] = *(const f32x4*)&smem[b * 288 + kc * 36 + kk4 * 4];
#pragma unroll
        for (int j = 0; j < 4; ++j) {
          float4 w = wreg[kk4 * 4 + j];
#pragma unroll
          for (int b = 0; b < 8; ++b) {
            float hj = hvv[b][j];
            a[b].x += w.x * hj; a[b].y += w.y * hj;
            a[b].z += w.z * hj; a[b].w += w.w * hj;
          }
        }
      }

      // ---- reduce-scatter over kc (R5 verbatim, static register indices) ----
#pragma unroll
      for (int j = 0; j < 4; ++j) {
        float4 snd = up0 ? a[j] : a[j + 4];
        float4 rcv = shfl_xor4(snd, 1);
        if (!up0) add4(a[j], rcv); else add4(a[j + 4], rcv);
      }
      float4 v0 = up0 ? a[4] : a[0];
      float4 v1 = up0 ? a[5] : a[1];
      float4 v2 = up0 ? a[6] : a[2];
      float4 v3 = up0 ? a[7] : a[3];
      {
        float4 snd = up1 ? v0 : v2;
        float4 rcv = shfl_xor4(snd, 2);
        if (!up1) add4(v0, rcv); else add4(v2, rcv);
        snd = up1 ? v1 : v3;
        rcv = shfl_xor4(snd, 2);
        if (!up1) add4(v1, rcv); else add4(v3, rcv);
      }
      float4 w0 = up1 ? v2 : v0;
      float4 w1 = up1 ? v3 : v1;
      {
        float4 snd = up2 ? w0 : w1;
        float4 rcv = shfl_xor4(snd, 4);
        if (!up2) add4(w0, rcv); else add4(w1, rcv);
      }
      float4 g4 = up2 ? w1 : w0;

      // ---- nonlinearity + publish (R5) ----
      float ii = g4.x + xg.x, ff = g4.y + xg.y, gg = g4.z + xg.z, oo = g4.w + xg.w;
      c_reg = sigm(ff) * c_reg + sigm(ii) * tanhf(gg);
      float hn = sigm(oo) * tanhf(c_reg);

      __hip_atomic_store(
          &hbuf[((size_t)(step % 3) * 2 + d) * BB * HH + (size_t)(bbase + b_own) * HH + uglob],
          hn, __ATOMIC_RELAXED, __HIP_MEMORY_SCOPE_AGENT);
      hloc[b_own * 33 + u] = hn;
      __syncthreads();   // drains vmcnt(0) per wave -> all h stores at LLC

      if (tid == 0)
        __hip_atomic_store(&tagsg[sl], step + 1, __ATOMIC_RELAXED,
                           __HIP_MEMORY_SCOPE_AGENT);

      // ---- feats slice contribution (R5 verbatim) ----
      {
        int b2 = tid >> 5, t = (tid >> 1) & 15, pr = tid & 1;
        float p = 0.f;
#pragma unroll
        for (int q = 0; q < 16; ++q)
          p += hloc[b2 * 33 + pr * 16 + q] * WoL[t * 33 + pr * 16 + q];
        p += __shfl_xor(p, 1);
        if (!pr)
          featsP[(((size_t)(d * 8 + sl) * BB + bbase + b2) * SS + s) * TT + t] = p;
      }
    }
  } else {
    // ================= xproj role: one 16-row tile, production-ordered =================
    int xb = blk - NRB;
    int d = xb & 1;
    int t16 = xb >> 1;
    int t = d ? (1023 - t16) : t16;   // d0: s ascending; d1: s descending

    if (tid < 16) {
      int sb = t * 16 + tid;
      int s = sb >> 7, b = sb & 127;
      idxs[tid] = sent[b * SS + s];
    }
    __syncthreads();
    for (int i = tid; i < 16 * 75; i += 256) {
      int r = i / 75, e4 = i % 75;
      *(f32x4*)&smem[r * 300 + e4 * 4] = ((const f32x4*)(emb + (size_t)idxs[r] * EE))[e4];
    }
    __syncthreads();

    const float* WT = WihT + (size_t)d * EE * G4;
    float acc0[16], acc1[16], acc2[16], acc3[16];
#pragma unroll
    for (int i = 0; i < 16; ++i) { acc0[i] = 0.f; acc1[i] = 0.f; acc2[i] = 0.f; acc3[i] = 0.f; }

    for (int e4 = 0; e4 < 75; ++e4) {
      const float* rowb = WT + (size_t)e4 * 4 * G4;
#pragma unroll
      for (int j = 0; j < 4; ++j) {
        const float* row = rowb + (size_t)j * G4;
        float w0 = row[tid];
        float w1 = row[tid + 256];
        float w2 = row[tid + 512];
        float w3 = row[tid + 768];
#pragma unroll
        for (int i = 0; i < 16; ++i) {
          float x = smem[i * 300 + e4 * 4 + j];
          acc0[i] += w0 * x; acc1[i] += w1 * x; acc2[i] += w2 * x; acc3[i] += w3 * x;
        }
      }
    }
    float b0 = bsum[d * G4 + tid];
    float b1 = bsum[d * G4 + tid + 256];
    float b2 = bsum[d * G4 + tid + 512];
    float b3 = bsum[d * G4 + tid + 768];
#pragma unroll
    for (int i = 0; i < 16; ++i) {
      int sb = t * 16 + i;
      int s = sb >> 7, b = sb & 127;
      float* base = xp4 + ((size_t)(d * SS + s) * BB + b) * G4 + tid * 4;
      store_f2_llc(base, acc0[i] + b0, acc1[i] + b1);
      store_f2_llc(base + 2, acc2[i] + b2, acc3[i] + b3);
    }
    __syncthreads();   // per-wave vmcnt drain -> all xp4 stores at LLC
    if (tid < 128) {
      int r = tid >> 3, sl = tid & 7;
      int sb = t * 16 + r;
      int s = sb >> 7, b = sb & 127;
      __hip_atomic_store(xstamp + ((size_t)(d * SS + s) * BB + b) * 8 + sl, 1,
                         __ATOMIC_RELAXED, __HIP_MEMORY_SCOPE_AGENT);
    }
  }
}

// ---------------- feats slice reduction ----------------
__global__ void k_fsum(const float* __restrict__ featsP, float* __restrict__ featsF) {
  int b = blockIdx.x;
  int tid = threadIdx.x;
  float acc[8];
#pragma unroll
  for (int j = 0; j < 8; ++j) acc[j] = 0.f;
  for (int dsl = 0; dsl < 16; ++dsl) {
    const float* fp = featsP + ((size_t)dsl * BB + b) * (SS * TT);
#pragma unroll
    for (int j = 0; j < 8; ++j) acc[j] += fp[j * 256 + tid];
  }
  float* fo = featsF + (size_t)b * (SS * TT);
#pragma unroll
  for (int j = 0; j < 8; ++j) fo[j * 256 + tid] = acc[j];
}

// ---------------- Viterbi (backpointers in LDS) ----------------
__global__ void k_viterbi(const float* __restrict__ featsF, const float* __restrict__ b_out,
                          const float* __restrict__ trans, float* __restrict__ out) {
  __shared__ float tr[TT * TT];
  __shared__ unsigned char bpl[16][SS][TT];
  int tid = threadIdx.x;
  if (tid < TT * TT) tr[tid] = trans[tid];
  __syncthreads();

  int bg = tid >> 4;
  int next = tid & 15;
  int b = blockIdx.x * 16 + bg;
  float fv = (next == START_TAG) ? 0.0f : NEGV;
  float bo = b_out[next];
  const float* fF = featsF + (size_t)b * SS * TT;

  for (int s = 0; s < SS; ++s) {
    float best = -INFINITY; int arg = 0;
#pragma unroll
    for (int prev = 0; prev < TT; ++prev) {
      float fvp = __shfl(fv, prev, 16);
      float cand = fvp + tr[next * TT + prev];
      if (cand > best) { best = cand; arg = prev; }
    }
    float feat = fF[s * TT + next] + bo;
    fv = best + feat;
    bpl[bg][s][next] = (unsigned char)arg;
  }

  float bv = fv + tr[STOP_TAG * TT + next];
  int bi = next;
#pragma unroll
  for (int off = 8; off; off >>= 1) {
    float ov = __shfl_down(bv, off, 16);
    int oi = __shfl_down(bi, off, 16);
    if (ov > bv || (ov == bv && oi < bi)) { bv = ov; bi = oi; }
  }
  if (next == 0) {
    out[b] = bv;
    int tag = bi;
    float* po = out + BB + (size_t)b * SS;
    for (int s = SS - 1; s >= 0; --s) {
      po[s] = (float)tag;
      tag = bpl[bg][s][tag];
    }
  }
}

// ---------------- host ----------------
extern "C" void kernel_launch(void* const* d_in, const int* in_sizes, int n_in,
                              void* d_out, int out_size, void* d_ws, size_t ws_size,
                              hipStream_t stream) {
  const int*   sent  = (const int*)d_in[0];
  const float* emb   = (const float*)d_in[1];
  const float* Wih_f = (const float*)d_in[2];
  const float* Whh_f = (const float*)d_in[3];
  const float* bih_f = (const float*)d_in[4];
  const float* bhh_f = (const float*)d_in[5];
  const float* Wih_b = (const float*)d_in[6];
  const float* Whh_b = (const float*)d_in[7];
  const float* bih_b = (const float*)d_in[8];
  const float* bhh_b = (const float*)d_in[9];
  const float* Wout  = (const float*)d_in[10];
  const float* b_out = (const float*)d_in[11];
  const float* trans = (const float*)d_in[12];
  const float* h0    = (const float*)d_in[13];
  const float* c0    = (const float*)d_in[14];

  float* ws = (float*)d_ws;
  size_t off = 0;
  float* xp4    = ws + off; off += (size_t)2 * SS * BB * G4;          // 33,554,432 fl
  int*   xstamp = (int*)(ws + off); off += (size_t)2 * SS * BB * 8;   //    262,144 w
  float* WihT   = ws + off; off += (size_t)2 * EE * G4;               //    614,400
  float* Whh4   = ws + off; off += (size_t)2 * HH * G4;               //    524,288
  float* bsum   = ws + off; off += (size_t)2 * G4;                    //      2,048
  float* featsP = ws + off; off += (size_t)16 * BB * SS * TT;         //  4,194,304
  float* featsF = ws + off; off += (size_t)BB * SS * TT;              //    262,144
  float* hbuf   = ws + off; off += (size_t)3 * 2 * BB * HH;           //    196,608
  int*   ctr    = (int*)(ws + off); off += 32 * 256;                  //      8,192 w

  const int NPREP = 2 * EE * G4 + 2 * HH * G4 + 2 * G4 + 32 * 256 + 2 * SS * BB * 8;
  k_prep<<<(NPREP + 255) / 256, 256, 0, stream>>>(Wih_f, Whh_f, bih_f, bhh_f,
                                                  Wih_b, Whh_b, bih_b, bhh_b,
                                                  WihT, Whh4, bsum, ctr, xstamp);

  k_main<<<NRB + NXT, 256, 0, stream>>>((const float4*)Whh4, Wout, h0, c0,
                                        hbuf, featsP, ctr, xp4, xstamp,
                                        sent, emb, WihT, bsum);

  k_fsum<<<BB, 256, 0, stream>>>(featsP, featsF);
  k_viterbi<<<8, 256, 0, stream>>>(featsF, b_out, trans, (float*)d_out);
}

// Round 14
// 846.880 us; speedup vs baseline: 4.0330x; 1.3847x over previous
//
#include <hip/hip_runtime.h>
#include <math.h>
#include <stdint.h>

#define BB 128   // batch
#define SS 128   // seq len
#define EE 300   // embed dim
#define HH 256   // per-direction hidden
#define G4 1024  // 4*HH gate width
#define TT 16    // tagset
#define NEGV -10000.0f
#define START_TAG 14
#define STOP_TAG 15

typedef float f32x4 __attribute__((ext_vector_type(4)));
typedef int   i32x4 __attribute__((ext_vector_type(4)));

__device__ __forceinline__ float sigm(float x) { return 1.0f / (1.0f + expf(-x)); }

__device__ __forceinline__ float4 shfl_xor4(float4 v, int m) {
  float4 r;
  r.x = __shfl_xor(v.x, m); r.y = __shfl_xor(v.y, m);
  r.z = __shfl_xor(v.z, m); r.w = __shfl_xor(v.w, m);
  return r;
}
__device__ __forceinline__ void add4(float4& a, const float4& b) {
  a.x += b.x; a.y += b.y; a.z += b.z; a.w += b.w;
}

// LLC-coherent loads: sc0+sc1 bypass L1/L2 -> device coherent point. Same
// load/store class R5/R10 proved correct (552 us run, absmax 0).
__device__ __forceinline__ f32x4 load_f4_llc(const float* p) {
  f32x4 v;
  asm volatile("global_load_dwordx4 %0, %1, off sc0 sc1\n\t"
               "s_waitcnt vmcnt(0)"
               : "=v"(v) : "v"(p) : "memory");
  return v;
}
__device__ __forceinline__ void load_tags8(const int* p, i32x4& a, i32x4& b) {
  asm volatile("global_load_dwordx4 %0, %2, off sc0 sc1\n\t"
               "global_load_dwordx4 %1, %2, off offset:16 sc0 sc1\n\t"
               "s_waitcnt vmcnt(0)"
               : "=&v"(a), "=&v"(b) : "v"(p) : "memory");
}

// ---------------- prep: weight transposes (gate-interleaved) + bias + tag zero ----------------
// WihT[d][e][u*4+g] = Wih_d[g*256+u][e]   (gate-interleaved j')
// Whh4[d][k][u*4+g] = Whh_d[g*256+u][k]
// bsum[d][u*4+g]    = bih_d[g*256+u] + bhh_d[g*256+u]
__global__ void k_prep(const float* __restrict__ Wih_f, const float* __restrict__ Whh_f,
                       const float* __restrict__ bih_f, const float* __restrict__ bhh_f,
                       const float* __restrict__ Wih_b, const float* __restrict__ Whh_b,
                       const float* __restrict__ bih_b, const float* __restrict__ bhh_b,
                       float* __restrict__ WihT, float* __restrict__ Whh4,
                       float* __restrict__ bsum, int* __restrict__ ctr) {
  int id = blockIdx.x * blockDim.x + threadIdx.x;
  const int N1 = 2 * EE * G4;
  const int N2 = 2 * HH * G4;
  const int N3 = 2 * G4;
  const int N4 = 64 * 256;   // tag regions
  if (id < N1) {
    int d = id / (EE * G4); int r = id % (EE * G4);
    int e = r / G4; int q = r % G4; int u = q >> 2; int g = q & 3;
    const float* W = d ? Wih_b : Wih_f;
    WihT[id] = W[(g * HH + u) * EE + e];
  } else if (id < N1 + N2) {
    int t = id - N1;
    int d = t / (HH * G4); int r = t % (HH * G4);
    int k = r / G4; int q = r % G4; int u = q >> 2; int g = q & 3;
    const float* W = d ? Whh_b : Whh_f;
    Whh4[t] = W[(g * HH + u) * HH + k];
  } else if (id < N1 + N2 + N3) {
    int t = id - N1 - N2;
    int d = t / G4; int q = t % G4; int u = q >> 2; int g = q & 3;
    int j = g * HH + u;
    bsum[t] = d ? (bih_b[j] + bhh_b[j]) : (bih_f[j] + bhh_f[j]);
  } else if (id < N1 + N2 + N3 + N4) {
    ctr[id - N1 - N2 - N3] = 0;
  }
}

// ---------------- input projection GEMM (gathered), 8i x 8j' tiling ----------------
// LDS-balance: 8-row i-tile halves ds_read_b128 count vs the 16i x 4j version
// (600/thread vs 1200), trading for 2x W-row traffic from L2 (overlappable).
// Output layout: float4 per u = (i,f,g,o) — matches k_recur's xg consumption.
__global__ void k_xproj(const int* __restrict__ sent, const float* __restrict__ emb,
                        const float* __restrict__ WihT, const float* __restrict__ bsum,
                        float4* __restrict__ xp4) {
  __shared__ __align__(16) float xs[16][EE];
  __shared__ int idxs[16];
  int blk = blockIdx.x;
  int d = blk >> 10;
  int tile = blk & 1023;
  int tid = threadIdx.x;
  if (tid < 16) {
    int sb = tile * 16 + tid;
    int s = sb >> 7, b = sb & 127;
    idxs[tid] = sent[b * SS + s];
  }
  __syncthreads();
  for (int t = tid; t < 16 * 75; t += 256) {
    int i = t / 75, e4 = t % 75;
    ((f32x4*)&xs[i][0])[e4] = ((const f32x4*)(emb + (size_t)idxs[i] * EE))[e4];
  }
  __syncthreads();

  int jg = tid & 127;        // 8 consecutive j' = 2 u's x 4 gates
  int ig = tid >> 7;         // 8-row i-group
  const float* WT = WihT + (size_t)d * EE * G4 + jg * 8;

  f32x4 accA[8], accB[8];
#pragma unroll
  for (int ii = 0; ii < 8; ++ii) {
    accA[ii] = (f32x4){0.f, 0.f, 0.f, 0.f};
    accB[ii] = (f32x4){0.f, 0.f, 0.f, 0.f};
  }

  for (int e4 = 0; e4 < 75; ++e4) {
    f32x4 xv[8];
#pragma unroll
    for (int ii = 0; ii < 8; ++ii)
      xv[ii] = *(const f32x4*)&xs[ig * 8 + ii][e4 * 4];
#pragma unroll
    for (int e = 0; e < 4; ++e) {
      const float* row = WT + (size_t)(e4 * 4 + e) * G4;
      f32x4 wa = *(const f32x4*)row;
      f32x4 wb = *(const f32x4*)(row + 4);
#pragma unroll
      for (int ii = 0; ii < 8; ++ii) {
        float x = xv[ii][e];
        accA[ii] += wa * x;
        accB[ii] += wb * x;
      }
    }
  }

  f32x4 ba = *(const f32x4*)&bsum[d * G4 + jg * 8];
  f32x4 bb = *(const f32x4*)&bsum[d * G4 + jg * 8 + 4];
#pragma unroll
  for (int ii = 0; ii < 8; ++ii) {
    int sb = tile * 16 + ig * 8 + ii;
    int s = sb >> 7, b = sb & 127;
    float* xp = (float*)(xp4 + ((size_t)(d * SS + s) * BB + b) * HH);
    *(f32x4*)&xp[jg * 8]     = accA[ii] + ba;
    *(f32x4*)&xp[jg * 8 + 4] = accB[ii] + bb;
  }
}

// ---------------- recurrent LSTM: R5 protocol, 2 co-resident blocks/CU (R10 verbatim) ----------------
// grid 512: blk = d*256 + bg*8 + sl (bg in [0,32), 4 batches each). 256 thr:
// tid = u*8 + kc. Per-group tag words posted by tid0 after a drain barrier; all
// threads poll the 32B tag line; h via relaxed agent stores + sc0sc1 loads at
// ring slot step%3. Weights stay register/AGPR-resident at launch_bounds(256,2).
__global__ __launch_bounds__(256, 2) void k_recur(
    const float4* __restrict__ xp4, const float4* __restrict__ Wg,
    const float* __restrict__ Wout, const float* __restrict__ h0,
    const float* __restrict__ c0, float* __restrict__ hbuf,
    float* __restrict__ featsP, int* __restrict__ ctr) {
  __shared__ __align__(16) float hshS[4 * 288];  // h staging, kc-swizzled
  __shared__ float hloc[4 * 33];                 // this step's h for feats
  __shared__ float WoL[16 * 33];                 // Wout slice

  int blk = blockIdx.x;
  int d = blk >> 8;
  int bg = (blk >> 3) & 31;
  int sl = blk & 7;
  int bbase = bg * 4;
  int tid = threadIdx.x;
  int u = tid >> 3, kc = tid & 7;
  int uglob = sl * 32 + u;
  int* tagsg = ctr + (d * 32 + bg) * 256 + 64;   // tags[sl] = last finished step + 1

  for (int i = tid; i < 16 * 32; i += 256) {
    int t = i >> 5, uu = i & 31;
    WoL[t * 33 + uu] = Wout[t * 512 + d * HH + sl * 32 + uu];
  }

  // Whh slice -> registers: wreg[kk] = Whh4[d][kc*32+kk][uglob] (i,f,g,o)
  float4 wreg[32];
  {
    const float4* Wd = Wg + (size_t)d * (HH * HH) + (size_t)(kc * 32) * HH + uglob;
#pragma unroll
    for (int kk = 0; kk < 32; ++kk) wreg[kk] = Wd[(size_t)kk * HH];
  }
  // owner map for 4-batch reduce-scatter over kc (lanes kc and kc^4 duplicate)
  int b_own = ((kc & 1) << 1) | ((kc >> 1) & 1);
  float c_reg = c0[((size_t)d * BB + bbase + b_own) * HH + uglob];
  bool up0 = (kc & 1), up1 = (kc & 2);

  // staging: thread handles (batch sb = tid>>6, k = (tid&63)*4 .. +3)
  int sb = tid >> 6;
  int sk = (tid & 63) * 4;
  int ldoff = sb * 288 + (sk >> 5) * 36 + (sk & 31);

  for (int step = 0; step < SS; ++step) {
    int s = d ? (SS - 1 - step) : step;
    // prefetch gate-input vec (h-independent), in flight during the wait
    float4 xg = xp4[(((size_t)d * SS + s) * BB + bbase + b_own) * HH + uglob];

    // ---- wait + stage h(step-1) ----
    float* ldst = &hshS[ldoff];
    if (step == 0) {
      const float* ps = h0 + ((size_t)d * BB + bbase + sb) * HH + sk;
      *(f32x4*)ldst = *(const f32x4*)ps;
    } else {
      i32x4 ta, tb;
      int m;
      do {
        load_tags8(tagsg, ta, tb);
        int m0 = min(min(ta[0], ta[1]), min(ta[2], ta[3]));
        int m1 = min(min(tb[0], tb[1]), min(tb[2], tb[3]));
        m = min(m0, m1);
      } while (m < step);
      const float* ps = hbuf + ((size_t)((step - 1) % 3) * 2 + d) * BB * HH +
                        (size_t)(bbase + sb) * HH + sk;
      *(f32x4*)ldst = load_f4_llc(ps);
    }
    __syncthreads();

    // ---- gate partials over this thread's 32-k chunk (4 batches) ----
    float4 a[4];
#pragma unroll
    for (int b = 0; b < 4; ++b) a[b] = make_float4(0.f, 0.f, 0.f, 0.f);
#pragma unroll
    for (int kk4 = 0; kk4 < 8; ++kk4) {
      float hvv[4][4];
#pragma unroll
      for (int b = 0; b < 4; ++b)
        *(f32x4*)&hvv[b][0] = *(const f32x4*)&hshS[b * 288 + kc * 36 + kk4 * 4];
#pragma unroll
      for (int j = 0; j < 4; ++j) {
        float4 w = wreg[kk4 * 4 + j];
#pragma unroll
        for (int b = 0; b < 4; ++b) {
          float hj = hvv[b][j];
          a[b].x += w.x * hj; a[b].y += w.y * hj;
          a[b].z += w.z * hj; a[b].w += w.w * hj;
        }
      }
    }

    // ---- reduce-scatter over kc (3 rounds; kc^4 lanes duplicate, benign) ----
#pragma unroll
    for (int j = 0; j < 2; ++j) {
      float4 snd = up0 ? a[j] : a[j + 2];
      float4 rcv = shfl_xor4(snd, 1);
      if (!up0) add4(a[j], rcv); else add4(a[j + 2], rcv);
    }
    float4 v0 = up0 ? a[2] : a[0];
    float4 v1 = up0 ? a[3] : a[1];
    {
      float4 snd = up1 ? v0 : v1;
      float4 rcv = shfl_xor4(snd, 2);
      if (!up1) add4(v0, rcv); else add4(v1, rcv);
    }
    float4 keep = up1 ? v1 : v0;
    {
      float4 rcv = shfl_xor4(keep, 4);
      add4(keep, rcv);
    }

    // ---- nonlinearity + publish ----
    float ii = keep.x + xg.x, ff = keep.y + xg.y;
    float gg = keep.z + xg.z, oo = keep.w + xg.w;
    c_reg = sigm(ff) * c_reg + sigm(ii) * tanhf(gg);
    float hn = sigm(oo) * tanhf(c_reg);

    if (kc < 4) {
      __hip_atomic_store(
          &hbuf[((size_t)(step % 3) * 2 + d) * BB * HH + (size_t)(bbase + b_own) * HH + uglob],
          hn, __ATOMIC_RELAXED, __HIP_MEMORY_SCOPE_AGENT);
      hloc[b_own * 33 + u] = hn;
    }
    __syncthreads();   // drains vmcnt(0) per wave -> all h stores at LLC

    // post the signal ASAP, then feats (overlaps other blocks' spin-exit)
    if (tid == 0)
      __hip_atomic_store(&tagsg[sl], step + 1, __ATOMIC_RELAXED,
                         __HIP_MEMORY_SCOPE_AGENT);

    // feats slice contribution: 256 thr = (b2, t, pr4)
    {
      int b2 = tid >> 6, t = (tid >> 2) & 15, pr = tid & 3;
      float p = 0.f;
#pragma unroll
      for (int q = 0; q < 8; ++q)
        p += hloc[b2 * 33 + pr * 8 + q] * WoL[t * 33 + pr * 8 + q];
      p += __shfl_xor(p, 1);
      p += __shfl_xor(p, 2);
      if (pr == 0)
        featsP[(((size_t)(d * 8 + sl) * BB + bbase + b2) * SS + s) * TT + t] = p;
    }
  }
}

// ---------------- feats slice reduction ----------------
__global__ void k_fsum(const float* __restrict__ featsP, float* __restrict__ featsF) {
  int b = blockIdx.x;
  int tid = threadIdx.x;
  float acc[8];
#pragma unroll
  for (int j = 0; j < 8; ++j) acc[j] = 0.f;
  for (int dsl = 0; dsl < 16; ++dsl) {
    const float* fp = featsP + ((size_t)dsl * BB + b) * (SS * TT);
#pragma unroll
    for (int j = 0; j < 8; ++j) acc[j] += fp[j * 256 + tid];
  }
  float* fo = featsF + (size_t)b * (SS * TT);
#pragma unroll
  for (int j = 0; j < 8; ++j) fo[j * 256 + tid] = acc[j];
}

// ---------------- Viterbi (backpointers in LDS) ----------------
__global__ void k_viterbi(const float* __restrict__ featsF, const float* __restrict__ b_out,
                          const float* __restrict__ trans, float* __restrict__ out) {
  __shared__ float tr[TT * TT];
  __shared__ unsigned char bpl[16][SS][TT];   // 32 KB
  int tid = threadIdx.x;
  if (tid < TT * TT) tr[tid] = trans[tid];
  __syncthreads();

  int bg = tid >> 4;
  int next = tid & 15;
  int b = blockIdx.x * 16 + bg;
  float fv = (next == START_TAG) ? 0.0f : NEGV;
  float bo = b_out[next];
  const float* fF = featsF + (size_t)b * SS * TT;

  for (int s = 0; s < SS; ++s) {
    float best = -INFINITY; int arg = 0;
#pragma unroll
    for (int prev = 0; prev < TT; ++prev) {
      float fvp = __shfl(fv, prev, 16);
      float cand = fvp + tr[next * TT + prev];
      if (cand > best) { best = cand; arg = prev; }
    }
    float feat = fF[s * TT + next] + bo;
    fv = best + feat;
    bpl[bg][s][next] = (unsigned char)arg;
  }

  float bv = fv + tr[STOP_TAG * TT + next];
  int bi = next;
#pragma unroll
  for (int off = 8; off; off >>= 1) {
    float ov = __shfl_down(bv, off, 16);
    int oi = __shfl_down(bi, off, 16);
    if (ov > bv || (ov == bv && oi < bi)) { bv = ov; bi = oi; }
  }
  if (next == 0) {
    out[b] = bv;
    int tag = bi;
    float* po = out + BB + (size_t)b * SS;
    for (int s = SS - 1; s >= 0; --s) {
      po[s] = (float)tag;
      tag = bpl[bg][s][tag];
    }
  }
}

// ---------------- host ----------------
extern "C" void kernel_launch(void* const* d_in, const int* in_sizes, int n_in,
                              void* d_out, int out_size, void* d_ws, size_t ws_size,
                              hipStream_t stream) {
  const int*   sent  = (const int*)d_in[0];
  const float* emb   = (const float*)d_in[1];
  const float* Wih_f = (const float*)d_in[2];
  const float* Whh_f = (const float*)d_in[3];
  const float* bih_f = (const float*)d_in[4];
  const float* bhh_f = (const float*)d_in[5];
  const float* Wih_b = (const float*)d_in[6];
  const float* Whh_b = (const float*)d_in[7];
  const float* bih_b = (const float*)d_in[8];
  const float* bhh_b = (const float*)d_in[9];
  const float* Wout  = (const float*)d_in[10];
  const float* b_out = (const float*)d_in[11];
  const float* trans = (const float*)d_in[12];
  const float* h0    = (const float*)d_in[13];
  const float* c0    = (const float*)d_in[14];

  float* ws = (float*)d_ws;
  size_t off = 0;
  float* xproj  = ws + off; off += (size_t)2 * SS * BB * G4;          // 33,554,432 fl
  float* WihT   = ws + off; off += (size_t)2 * EE * G4;               //    614,400
  float* Whh4   = ws + off; off += (size_t)2 * HH * G4;               //    524,288
  float* bsum   = ws + off; off += (size_t)2 * G4;                    //      2,048
  float* featsP = ws + off; off += (size_t)16 * BB * SS * TT;         //  4,194,304
  float* featsF = ws + off; off += (size_t)BB * SS * TT;              //    262,144
  float* hbuf   = ws + off; off += (size_t)3 * 2 * BB * HH;           //    196,608
  int*   ctr    = (int*)(ws + off); off += 64 * 256;                  //     64 KB

  const int NPREP = 2 * EE * G4 + 2 * HH * G4 + 2 * G4 + 64 * 256;
  k_prep<<<(NPREP + 255) / 256, 256, 0, stream>>>(Wih_f, Whh_f, bih_f, bhh_f,
                                                  Wih_b, Whh_b, bih_b, bhh_b,
                                                  WihT, Whh4, bsum, ctr);
  k_xproj<<<2048, 256, 0, stream>>>(sent, emb, WihT, bsum, (float4*)xproj);

  {
    const float4* xp4c = (const float4*)xproj;
    const float4* Wgc  = (const float4*)Whh4;
    void* kargs[] = {(void*)&xp4c, (void*)&Wgc, (void*)&Wout, (void*)&h0,
                     (void*)&c0, (void*)&hbuf, (void*)&featsP, (void*)&ctr};
    hipError_t e = hipLaunchCooperativeKernel(k_recur, dim3(512), dim3(256),
                                              kargs, 0, stream);
    if (e != hipSuccess) {
      // plain launch: 512 blocks fit 2/CU at our VGPR/LDS usage -> all resident
      k_recur<<<512, 256, 0, stream>>>(xp4c, Wgc, Wout, h0, c0, hbuf, featsP, ctr);
    }
  }

  k_fsum<<<BB, 256, 0, stream>>>(featsP, featsF);
  k_viterbi<<<8, 256, 0, stream>>>(featsF, b_out, trans, (float*)d_out);
}